// Round 5
// baseline (95.349 us; speedup 1.0000x reference)
//
#include <hip/hip_runtime.h>

#define BB 8
#define CC 256
#define NN 4096
#define DD 32
#define NK 1024

typedef unsigned short u16;
typedef unsigned int   u32;
typedef __attribute__((ext_vector_type(8))) short bf16x8;
typedef __attribute__((ext_vector_type(4))) float f32x4;

#define MFMA16 __builtin_amdgcn_mfma_f32_16x16x32_bf16

// workspace offsets (in floats) — total 2,793,472 f = 11.2 MB
#define OFF_XKVT 0u          // [B][NK][CC] bf16   1,048,576 f
#define OFF_WVO  1048576u    // [CC][CC] bf16         32,768 f
#define OFF_WQB  1081344u    // [DD][CC] bf16          4,096 f
#define OFF_WKB  1085440u    // [DD][CC] bf16          4,096 f
#define OFF_QBF  1089536u    // [B][NN][DD] bf16     524,288 f
#define OFF_KBF  1613824u    // [B][NK][DD] bf16     131,072 f
#define OFF_VOBF 1744896u    // [B][CC][NK] bf16   1,048,576 f
// xT_bf [B][NN][CC] bf16 (16 MB) lives in d_out (dead before attn writes out)

__device__ __forceinline__ u16 f2bf(float f) {
    u32 u = __float_as_uint(f);
    u += 0x7FFFu + ((u >> 16) & 1u);      // RNE
    return (u16)(u >> 16);
}

__device__ __forceinline__ u32 cvt_pk_bf16(float lo, float hi) {
    u32 r;
    asm("v_cvt_pk_bf16_f32 %0, %1, %2" : "=v"(r) : "v"(lo), "v"(hi));
    return r;
}

// ---- prep: x[B,C,64,64] -> xT_bf[B][N][C] (transpose) + xkvT_bf[B][Nk][C] --
__launch_bounds__(256)
__global__ void prep_kernel(const float* __restrict__ x, u16* __restrict__ xT,
                            u16* __restrict__ xkvT) {
    __shared__ float xl[64 * 132];
    int blk = blockIdx.x;
    int b = blk & 7, rest = blk >> 3, cb = rest & 3, hb = rest >> 2;
    int c0 = cb * 64, n0 = hb * 128;
    int t = threadIdx.x;
    const float* xb = x + ((size_t)(b * CC + c0)) * NN + n0;
#pragma unroll
    for (int p = 0; p < 8; ++p) {
        int cr = p * 8 + (t >> 5);
        int ns = (t & 31) * 4;
        *(float4*)&xl[cr * 132 + ns] = *(const float4*)(xb + (size_t)cr * NN + ns);
    }
    __syncthreads();
    {
        int nl = t & 127, ch = t >> 7;
        u16* xp = xT + ((size_t)b * NN + n0 + nl) * CC + c0 + ch * 32;
        u32 wb[16];
#pragma unroll
        for (int j = 0; j < 16; ++j) {
            float a = xl[(ch * 32 + 2 * j) * 132 + nl];
            float c = xl[(ch * 32 + 2 * j + 1) * 132 + nl];
            wb[j] = (u32)f2bf(a) | ((u32)f2bf(c) << 16);
        }
#pragma unroll
        for (int j = 0; j < 4; ++j)
            *(uint4*)(xp + j * 8) = make_uint4(wb[4*j], wb[4*j+1], wb[4*j+2], wb[4*j+3]);
    }
    {
        int wk = t & 31, co = t >> 5;
        u32 pw[4];
#pragma unroll
        for (int j = 0; j < 4; ++j) {
            int cl0 = co * 8 + 2 * j;
            float s0 = 0.25f * (xl[cl0*132 + 2*wk] + xl[cl0*132 + 2*wk + 1]
                              + xl[cl0*132 + 64 + 2*wk] + xl[cl0*132 + 65 + 2*wk]);
            int cl1 = cl0 + 1;
            float s1 = 0.25f * (xl[cl1*132 + 2*wk] + xl[cl1*132 + 2*wk + 1]
                              + xl[cl1*132 + 64 + 2*wk] + xl[cl1*132 + 65 + 2*wk]);
            pw[j] = (u32)f2bf(s0) | ((u32)f2bf(s1) << 16);
        }
        u16* kp = xkvT + ((size_t)b * NK + hb * 32 + wk) * CC + c0 + co * 8;
        *(uint4*)kp = make_uint4(pw[0], pw[1], pw[2], pw[3]);
    }
}

// ---- weight prep -----------------------------------------------------------
__global__ void wprep_kernel(const float* __restrict__ wq, const float* __restrict__ wk,
                             const float* __restrict__ wv, const float* __restrict__ wo,
                             u16* __restrict__ wqb, u16* __restrict__ wkb,
                             u16* __restrict__ wvob) {
    int o = blockIdx.x, c = threadIdx.x;
    float acc = 0.f;
#pragma unroll 8
    for (int j = 0; j < CC; ++j)
        acc += wo[o * CC + j] * wv[j * CC + c];
    wvob[o * CC + c] = f2bf(acc);
    int id = blockIdx.x * 256 + threadIdx.x;
    if (id < DD * CC) {
        const float QS = 0.17677669529663687f * 1.4426950408889634f; // 1/sqrt(32)*log2e
        wqb[id] = f2bf(wq[id] * QS);
        wkb[id] = f2bf(wk[id]);
    }
}

// ---- q & k projections (MFMA) ----------------------------------------------
__launch_bounds__(256)
__global__ void qk_kernel(const u16* __restrict__ xT, const u16* __restrict__ xkvT,
                          const u16* __restrict__ wqb, const u16* __restrict__ wkb,
                          u16* __restrict__ qbf, u16* __restrict__ kbf) {
    int blk = blockIdx.x;
    const u16 *A, *Bw; u16* outp;
    if (blk < 256) {
        int b = blk & 7, rb = blk >> 3;
        A = xT + ((size_t)b * NN + rb * 128) * CC;
        Bw = wqb;
        outp = qbf + ((size_t)b * NN + rb * 128) * DD;
    } else {
        int k2 = blk - 256;
        int b = k2 & 7, rb = k2 >> 3;
        A = xkvT + ((size_t)b * NK + rb * 128) * CC;
        Bw = wkb;
        outp = kbf + ((size_t)b * NK + rb * 128) * DD;
    }
    int t = threadIdx.x, w = t >> 6, l = t & 63, l15 = l & 15, lg = l >> 4;
    const u16* Aw = A + (size_t)(w * 32) * CC;
    f32x4 acc[2][2];
    const f32x4 fz = {0.f, 0.f, 0.f, 0.f};
    acc[0][0] = fz; acc[0][1] = fz; acc[1][0] = fz; acc[1][1] = fz;
#pragma unroll
    for (int ks = 0; ks < 8; ++ks) {
        int k0 = ks * 32 + lg * 8;
        bf16x8 a0 = *(const bf16x8*)(Aw + (size_t)l15 * CC + k0);
        bf16x8 a1 = *(const bf16x8*)(Aw + (size_t)(16 + l15) * CC + k0);
        bf16x8 b0 = *(const bf16x8*)(Bw + (size_t)l15 * CC + k0);
        bf16x8 b1 = *(const bf16x8*)(Bw + (size_t)(16 + l15) * CC + k0);
        acc[0][0] = MFMA16(a0, b0, acc[0][0], 0, 0, 0);
        acc[0][1] = MFMA16(a0, b1, acc[0][1], 0, 0, 0);
        acc[1][0] = MFMA16(a1, b0, acc[1][0], 0, 0, 0);
        acc[1][1] = MFMA16(a1, b1, acc[1][1], 0, 0, 0);
    }
    u16* op = outp + (size_t)(w * 32) * DD;
#pragma unroll
    for (int i = 0; i < 2; ++i)
#pragma unroll
        for (int j = 0; j < 2; ++j)
#pragma unroll
            for (int r2 = 0; r2 < 4; ++r2)
                op[(size_t)(i * 16 + lg * 4 + r2) * DD + j * 16 + l15] = f2bf(acc[i][j][r2]);
}

// ---- vo projection (MFMA) ---------------------------------------------------
__launch_bounds__(256)
__global__ void vo_kernel(const u16* __restrict__ xkvT, const u16* __restrict__ wvob,
                          u16* __restrict__ vobf) {
    int blk = blockIdx.x;
    int b = blk & 7, r = blk >> 3, ob = r & 3, mb = r >> 2;
    int t = threadIdx.x, w = t >> 6, l = t & 63, l15 = l & 15, lg = l >> 4;
    int o0 = ob * 64 + (w & 1) * 32;
    int m0 = mb * 128 + (w >> 1) * 64;
    const u16* ab = wvob + (size_t)o0 * CC;
    const u16* bb = xkvT + ((size_t)b * NK + m0) * CC;
    f32x4 acc[2][4];
    const f32x4 fz = {0.f, 0.f, 0.f, 0.f};
#pragma unroll
    for (int i = 0; i < 2; ++i)
#pragma unroll
        for (int j = 0; j < 4; ++j) acc[i][j] = fz;
#pragma unroll
    for (int ks = 0; ks < 8; ++ks) {
        int k0 = ks * 32 + lg * 8;
        bf16x8 a0 = *(const bf16x8*)(ab + (size_t)l15 * CC + k0);
        bf16x8 a1 = *(const bf16x8*)(ab + (size_t)(16 + l15) * CC + k0);
        bf16x8 bv0 = *(const bf16x8*)(bb + (size_t)(l15) * CC + k0);
        bf16x8 bv1 = *(const bf16x8*)(bb + (size_t)(16 + l15) * CC + k0);
        bf16x8 bv2 = *(const bf16x8*)(bb + (size_t)(32 + l15) * CC + k0);
        bf16x8 bv3 = *(const bf16x8*)(bb + (size_t)(48 + l15) * CC + k0);
        acc[0][0] = MFMA16(a0, bv0, acc[0][0], 0, 0, 0);
        acc[0][1] = MFMA16(a0, bv1, acc[0][1], 0, 0, 0);
        acc[0][2] = MFMA16(a0, bv2, acc[0][2], 0, 0, 0);
        acc[0][3] = MFMA16(a0, bv3, acc[0][3], 0, 0, 0);
        acc[1][0] = MFMA16(a1, bv0, acc[1][0], 0, 0, 0);
        acc[1][1] = MFMA16(a1, bv1, acc[1][1], 0, 0, 0);
        acc[1][2] = MFMA16(a1, bv2, acc[1][2], 0, 0, 0);
        acc[1][3] = MFMA16(a1, bv3, acc[1][3], 0, 0, 0);
    }
    u16* vp = vobf + ((size_t)b * CC + o0) * NK + m0;
#pragma unroll
    for (int i = 0; i < 2; ++i)
#pragma unroll
        for (int j = 0; j < 4; ++j)
#pragma unroll
            for (int r2 = 0; r2 < 4; ++r2)
                vp[(size_t)(i * 16 + lg * 4 + r2) * NK + j * 16 + l15] = f2bf(acc[i][j][r2]);
}

// ---------------- fused flash attention (MFMA) + epilogue -------------------
// block: 8 waves (512 thr), 64 q-rows; wave (wm,wo): m-half wm, o-slice wo*64,
// QK-tile wo of stream wm. 16 iters. lgkm-only barrier; partial (acc,rs) over
// m-halves combined in-block at the end (softmax is max-free -> addable).
__launch_bounds__(512, 4)
__global__ void attn_kernel(const u16* __restrict__ qbf, const u16* __restrict__ kbf,
                            const u16* __restrict__ vobf, const float* __restrict__ x,
                            const float* __restrict__ gamma, float* __restrict__ out) {
    __shared__ __align__(16) u16   p_lds[2][2][64 * 40];  // [wm][buf][n][m] 20 KB
    __shared__ __align__(16) float rs_lds[2][64];

    const int t   = threadIdx.x;
    const int wv  = t >> 6, l = t & 63;
    const int wm  = wv >> 2, wo = wv & 3;
    const int l15 = l & 15, lg = l >> 4;
    const int b   = blockIdx.x & 7;              // batch -> XCD pin
    const int n0  = (blockIdx.x >> 3) << 6;      // 64-row tile

    const u16* qb = qbf  + (size_t)b * NN * DD;
    const u16* kb = kbf  + (size_t)b * NK * DD;
    const u16* vb = vobf + (size_t)b * CC * NK;

    // Q fragment (B operand): col n = n0 + wo*16 + l15, k = lg*8..+7
    bf16x8 qf = *(const bf16x8*)(qb + (size_t)(n0 + wo * 16 + l15) * DD + lg * 8);

    const int mbase = wm * 512;                  // this wave's m-half
    const u16* kfp = kb + (size_t)(mbase + l15) * DD + lg * 8;           // + mm*DD
    const u16* vbl = vb + (size_t)(wo * 64 + l15) * NK + mbase + lg * 8; // + of*16*NK + mm
    u16*       pwp = &p_lds[wm][0][(wo * 16 + l15) * 40 + lg * 4];       // + buf*2560
    const u16* prp = &p_lds[wm][0][l15 * 40 + lg * 8];                   // + buf*2560 + j*640

    f32x4 acc[4][4];
    const f32x4 fz = {0.f, 0.f, 0.f, 0.f};
#pragma unroll
    for (int j = 0; j < 4; ++j)
#pragma unroll
        for (int of = 0; of < 4; ++of) acc[j][of] = fz;
    float rs = 0.f;

    bf16x8 kf0 = *(const bf16x8*)(kfp);
    bf16x8 kf1 = *(const bf16x8*)(kfp + 16 * DD);

#pragma unroll 2
    for (int i = 0; i < 16; ++i) {
        const int mm  = i * 32;                  // m within half
        const int buf = i & 1;
        // ---- VO B-fragments (L2) — stay in flight across the lgkm barrier ---
        bf16x8 vof[4];
#pragma unroll
        for (int of = 0; of < 4; ++of)
            vof[of] = *(const bf16x8*)(vbl + (size_t)(of * 16) * NK + mm);
        // ---- S^T tile: lane n = l15, m = mbase + mm + lg*4 + r (+16) --------
        f32x4 c0 = MFMA16(kf0, qf, fz, 0, 0, 0);
        f32x4 c1 = MFMA16(kf1, qf, fz, 0, 0, 0);
        float e0 = __builtin_amdgcn_exp2f(c0[0]);
        float e1 = __builtin_amdgcn_exp2f(c0[1]);
        float e2 = __builtin_amdgcn_exp2f(c0[2]);
        float e3 = __builtin_amdgcn_exp2f(c0[3]);
        float e4 = __builtin_amdgcn_exp2f(c1[0]);
        float e5 = __builtin_amdgcn_exp2f(c1[1]);
        float e6 = __builtin_amdgcn_exp2f(c1[2]);
        float e7 = __builtin_amdgcn_exp2f(c1[3]);
        rs += (e0 + e1 + e2 + e3) + (e4 + e5 + e6 + e7);
        uint2 pw0, pw1;
        pw0.x = cvt_pk_bf16(e0, e1);
        pw0.y = cvt_pk_bf16(e2, e3);
        pw1.x = cvt_pk_bf16(e4, e5);
        pw1.y = cvt_pk_bf16(e6, e7);
        u16* pw = pwp + buf * 2560;
        *(uint2*)pw        = pw0;                // m-local lg*4..+3
        *(uint2*)(pw + 16) = pw1;                // m-local 16+lg*4..+3
        // ---- barrier: drain LDS only; global loads stay outstanding ---------
        asm volatile("s_waitcnt lgkmcnt(0)" ::: "memory");
        __builtin_amdgcn_s_barrier();
        // ---- next-iter K prefetch (post-barrier: ~full iter of cover) -------
        bf16x8 kn0, kn1;
        if (i < 15) {
            kn0 = *(const bf16x8*)(kfp + (size_t)(mm + 32) * DD);
            kn1 = *(const bf16x8*)(kfp + (size_t)(mm + 48) * DD);
        }
        // ---- PV: 4 n-subtiles x 4 o-frags -----------------------------------
        const u16* pr = prp + buf * 2560;
#pragma unroll
        for (int j = 0; j < 4; ++j) {
            bf16x8 pa = *(const bf16x8*)(pr + j * 640);
#pragma unroll
            for (int of = 0; of < 4; ++of)
                acc[j][of] = MFMA16(pa, vof[of], acc[j][of], 0, 0, 0);
        }
        kf0 = kn0; kf1 = kn1;
    }

    // ---- row sums for this wave's 16 QK rows (half-m) -----------------------
    rs += __shfl_xor(rs, 16);
    rs += __shfl_xor(rs, 32);
    if (l < 16) rs_lds[wm][wo * 16 + l] = rs;

    // ---- combine m-half partials: wm=1 -> wm=0 via reused p_lds -------------
    __syncthreads();
    float* cbuf = (float*)p_lds;                 // 5120 floats available
#pragma unroll
    for (int r = 0; r < 4; ++r) {
        if (wm == 1) {
#pragma unroll
            for (int of = 0; of < 4; ++of)
                *(float4*)&cbuf[((wo * 64 + l) * 16) + of * 4] =
                    make_float4(acc[r][of][0], acc[r][of][1], acc[r][of][2], acc[r][of][3]);
        }
        __syncthreads();
        if (wm == 0) {
#pragma unroll
            for (int of = 0; of < 4; ++of) {
                float4 p = *(const float4*)&cbuf[((wo * 64 + l) * 16) + of * 4];
                acc[r][of][0] += p.x; acc[r][of][1] += p.y;
                acc[r][of][2] += p.z; acc[r][of][3] += p.w;
            }
        }
        __syncthreads();
    }

    // ---- epilogue (wm=0 waves): out[b][o][n] = x + g * O / rs ---------------
    if (wm == 0) {
        float g = gamma[0];
#pragma unroll
        for (int j = 0; j < 4; ++j) {
            float r0 = rs_lds[0][j * 16 + lg * 4 + 0] + rs_lds[1][j * 16 + lg * 4 + 0];
            float r1 = rs_lds[0][j * 16 + lg * 4 + 1] + rs_lds[1][j * 16 + lg * 4 + 1];
            float r2 = rs_lds[0][j * 16 + lg * 4 + 2] + rs_lds[1][j * 16 + lg * 4 + 2];
            float r3 = rs_lds[0][j * 16 + lg * 4 + 3] + rs_lds[1][j * 16 + lg * 4 + 3];
            float fa0 = g / r0, fa1 = g / r1, fa2 = g / r2, fa3 = g / r3;
#pragma unroll
            for (int of = 0; of < 4; ++of) {
                size_t base = ((size_t)(b * CC + wo * 64 + of * 16 + l15)) * NN
                            + n0 + j * 16 + lg * 4;
                float4 xv = *(const float4*)(x + base);
                float4 ov;
                ov.x = xv.x + acc[j][of][0] * fa0;
                ov.y = xv.y + acc[j][of][1] * fa1;
                ov.z = xv.z + acc[j][of][2] * fa2;
                ov.w = xv.w + acc[j][of][3] * fa3;
                *(float4*)(out + base) = ov;
            }
        }
    }
}

extern "C" void kernel_launch(void* const* d_in, const int* in_sizes, int n_in,
                              void* d_out, int out_size, void* d_ws, size_t ws_size,
                              hipStream_t stream) {
    const float* x     = (const float*)d_in[0];
    const float* wq    = (const float*)d_in[1];
    const float* wk    = (const float*)d_in[2];
    const float* wv    = (const float*)d_in[3];
    const float* wo    = (const float*)d_in[4];
    const float* gamma = (const float*)d_in[5];
    float* out = (float*)d_out;
    float* ws  = (float*)d_ws;

    u16* xkvT = (u16*)(ws + OFF_XKVT);
    u16* wvob = (u16*)(ws + OFF_WVO);
    u16* wqb  = (u16*)(ws + OFF_WQB);
    u16* wkb  = (u16*)(ws + OFF_WKB);
    u16* qbf  = (u16*)(ws + OFF_QBF);
    u16* kbf  = (u16*)(ws + OFF_KBF);
    u16* vobf = (u16*)(ws + OFF_VOBF);
    u16* xT   = (u16*)d_out;     // 16 MB scratch in d_out; dead before attn writes

    prep_kernel <<<dim3(1024), dim3(256), 0, stream>>>(x, xT, xkvT);
    wprep_kernel<<<dim3(256),  dim3(256), 0, stream>>>(wq, wk, wv, wo, wqb, wkb, wvob);
    qk_kernel   <<<dim3(320),  dim3(256), 0, stream>>>(xT, xkvT, wqb, wkb, qbf, kbf);
    vo_kernel   <<<dim3(256),  dim3(256), 0, stream>>>(xkvT, wvob, vobf);
    attn_kernel <<<dim3(512),  dim3(512), 0, stream>>>(qbf, kbf, vobf, x, gamma, out);
}

// Round 6
// 70.285 us; speedup vs baseline: 1.3566x; 1.3566x over previous
//
#include <hip/hip_runtime.h>

#define BB 8
#define CC 256
#define NN 4096
#define DD 32
#define NK 1024

typedef unsigned short u16;
typedef unsigned int   u32;
typedef __attribute__((ext_vector_type(8))) short bf16x8;
typedef __attribute__((ext_vector_type(4))) float f32x4;

#define MFMA16 __builtin_amdgcn_mfma_f32_16x16x32_bf16

// workspace offsets (in floats) — total 2,793,472 f = 11.2 MB
#define OFF_XKVT 0u          // [B][NK][CC] bf16        1,048,576 f
#define OFF_WVO  1048576u    // [CC][CC] bf16              32,768 f
#define OFF_WQB  1081344u    // [DD][CC] bf16               4,096 f
#define OFF_WKB  1085440u    // [DD][CC] bf16               4,096 f
#define OFF_QF   1089536u    // qF  [B][256 n16][64][8]   524,288 f
#define OFF_KF   1613824u    // kF  [B][64 m16][64][8]    131,072 f
#define OFF_VOF  1744896u    // voF [B][32 m32][16 o16][64][8] 1,048,576 f
// xT_bf [B][NN][CC] bf16 (16 MB) lives in d_out (dead before attn writes out)

__device__ __forceinline__ u16 f2bf(float f) {
    u32 u = __float_as_uint(f);
    u += 0x7FFFu + ((u >> 16) & 1u);      // RNE
    return (u16)(u >> 16);
}

__device__ __forceinline__ u32 cvt_pk_bf16(float lo, float hi) {
    u32 r;
    asm("v_cvt_pk_bf16_f32 %0, %1, %2" : "=v"(r) : "v"(lo), "v"(hi));
    return r;
}

// ==== fused prep (blocks 0..1023) + weight prep (blocks 1024..1279) =========
__launch_bounds__(256)
__global__ void prepw_kernel(const float* __restrict__ x,
                             const float* __restrict__ wq, const float* __restrict__ wk,
                             const float* __restrict__ wv, const float* __restrict__ wo,
                             u16* __restrict__ xT, u16* __restrict__ xkvT,
                             u16* __restrict__ wqb, u16* __restrict__ wkb,
                             u16* __restrict__ wvob) {
    int t = threadIdx.x;
    if (blockIdx.x < 1024) {
        __shared__ float xl[64 * 132];
        int blk = blockIdx.x;
        int b = blk & 7, rest = blk >> 3, cb = rest & 3, hb = rest >> 2;
        int c0 = cb * 64, n0 = hb * 128;
        const float* xb = x + ((size_t)(b * CC + c0)) * NN + n0;
#pragma unroll
        for (int p = 0; p < 8; ++p) {
            int cr = p * 8 + (t >> 5);
            int ns = (t & 31) * 4;
            *(float4*)&xl[cr * 132 + ns] = *(const float4*)(xb + (size_t)cr * NN + ns);
        }
        __syncthreads();
        {
            int nl = t & 127, ch = t >> 7;
            u16* xp = xT + ((size_t)b * NN + n0 + nl) * CC + c0 + ch * 32;
            u32 wb[16];
#pragma unroll
            for (int j = 0; j < 16; ++j) {
                float a = xl[(ch * 32 + 2 * j) * 132 + nl];
                float c = xl[(ch * 32 + 2 * j + 1) * 132 + nl];
                wb[j] = (u32)f2bf(a) | ((u32)f2bf(c) << 16);
            }
#pragma unroll
            for (int j = 0; j < 4; ++j)
                *(uint4*)(xp + j * 8) = make_uint4(wb[4*j], wb[4*j+1], wb[4*j+2], wb[4*j+3]);
        }
        {
            int wk2 = t & 31, co = t >> 5;
            u32 pw[4];
#pragma unroll
            for (int j = 0; j < 4; ++j) {
                int cl0 = co * 8 + 2 * j;
                float s0 = 0.25f * (xl[cl0*132 + 2*wk2] + xl[cl0*132 + 2*wk2 + 1]
                                  + xl[cl0*132 + 64 + 2*wk2] + xl[cl0*132 + 65 + 2*wk2]);
                int cl1 = cl0 + 1;
                float s1 = 0.25f * (xl[cl1*132 + 2*wk2] + xl[cl1*132 + 2*wk2 + 1]
                                  + xl[cl1*132 + 64 + 2*wk2] + xl[cl1*132 + 65 + 2*wk2]);
                pw[j] = (u32)f2bf(s0) | ((u32)f2bf(s1) << 16);
            }
            u16* kp = xkvT + ((size_t)b * NK + hb * 32 + wk2) * CC + c0 + co * 8;
            *(uint4*)kp = make_uint4(pw[0], pw[1], pw[2], pw[3]);
        }
    } else {
        int o = blockIdx.x - 1024, c = t;
        float acc = 0.f;
#pragma unroll 8
        for (int j = 0; j < CC; ++j)
            acc += wo[o * CC + j] * wv[j * CC + c];
        wvob[o * CC + c] = f2bf(acc);
        int id = o * 256 + t;
        if (id < DD * CC) {
            const float QS = 0.17677669529663687f * 1.4426950408889634f; // 1/sqrt(32)*log2e
            wqb[id] = f2bf(wq[id] * QS);
            wkb[id] = f2bf(wk[id]);
        }
    }
}

// ==== fused projections: qk (blocks 0..319) + vo (blocks 320..575) ==========
// q/k outputs packed as MFMA fragments: qF[b][n16][lane][8], kF[b][m16][lane][8]
// vo packed: voF[b][m32][o16][lane][8]  (lane = (mlocal>>3)*16 + (o&15), j = m&7)
__launch_bounds__(256)
__global__ void proj_kernel(const u16* __restrict__ xT, const u16* __restrict__ xkvT,
                            const u16* __restrict__ wqb, const u16* __restrict__ wkb,
                            const u16* __restrict__ wvob,
                            u16* __restrict__ qF, u16* __restrict__ kF,
                            u16* __restrict__ voF) {
    int t = threadIdx.x, w = t >> 6, l = t & 63, l15 = l & 15, lg = l >> 4;
    const f32x4 fz = {0.f, 0.f, 0.f, 0.f};
    if (blockIdx.x < 320) {
        int blk = blockIdx.x;
        const u16 *A, *Bw; u16* outp; int tb4, b;
        if (blk < 256) {
            b = blk & 7;
            int rb = blk >> 3;
            A = xT + ((size_t)b * NN + rb * 128) * CC;
            Bw = wqb;
            outp = qF + (size_t)b * 256 * 512;
            tb4 = rb * 8;                         // row-tile base (16-row units)
        } else {
            int k2 = blk - 256;
            b = k2 & 7;
            int rb = k2 >> 3;
            A = xkvT + ((size_t)b * NK + rb * 128) * CC;
            Bw = wkb;
            outp = kF + (size_t)b * 64 * 512;
            tb4 = rb * 8;
        }
        const u16* Aw = A + (size_t)(w * 32) * CC;
        f32x4 acc[2][2];
        acc[0][0] = fz; acc[0][1] = fz; acc[1][0] = fz; acc[1][1] = fz;
#pragma unroll
        for (int ks = 0; ks < 8; ++ks) {
            int k0 = ks * 32 + lg * 8;
            bf16x8 a0 = *(const bf16x8*)(Aw + (size_t)l15 * CC + k0);
            bf16x8 a1 = *(const bf16x8*)(Aw + (size_t)(16 + l15) * CC + k0);
            bf16x8 b0 = *(const bf16x8*)(Bw + (size_t)l15 * CC + k0);
            bf16x8 b1 = *(const bf16x8*)(Bw + (size_t)(16 + l15) * CC + k0);
            acc[0][0] = MFMA16(a0, b0, acc[0][0], 0, 0, 0);
            acc[0][1] = MFMA16(a0, b1, acc[0][1], 0, 0, 0);
            acc[1][0] = MFMA16(a1, b0, acc[1][0], 0, 0, 0);
            acc[1][1] = MFMA16(a1, b1, acc[1][1], 0, 0, 0);
        }
        // scatter into fragment-packed layout:
        // row r = tile (tb4 + w*2 + i), rlocal = lg*4+r2 ; col d = jj*16+l15
        // idx = ((tile)*64 + (d>>3)*16 + rlocal)*8 + (d&7)
#pragma unroll
        for (int i = 0; i < 2; ++i)
#pragma unroll
            for (int jj = 0; jj < 2; ++jj)
#pragma unroll
                for (int r2 = 0; r2 < 4; ++r2) {
                    int tile = tb4 + w * 2 + i;
                    int dhi = jj * 2 + (l15 >> 3);
                    outp[((size_t)tile * 64 + dhi * 16 + lg * 4 + r2) * 8 + (l15 & 7)]
                        = f2bf(acc[i][jj][r2]);
                }
    } else {
        int blk = blockIdx.x - 320;
        int b = blk & 7, r = blk >> 3, ob = r & 3, mb = r >> 2;
        int o0 = ob * 64 + (w & 1) * 32;
        int m0 = mb * 128 + (w >> 1) * 64;
        const u16* ab = wvob + (size_t)o0 * CC;
        const u16* bb = xkvT + ((size_t)b * NK + m0) * CC;
        f32x4 acc[2][4];
#pragma unroll
        for (int i = 0; i < 2; ++i)
#pragma unroll
            for (int j = 0; j < 4; ++j) acc[i][j] = fz;
#pragma unroll
        for (int ks = 0; ks < 8; ++ks) {
            int k0 = ks * 32 + lg * 8;
            bf16x8 a0 = *(const bf16x8*)(ab + (size_t)l15 * CC + k0);
            bf16x8 a1 = *(const bf16x8*)(ab + (size_t)(16 + l15) * CC + k0);
            bf16x8 bv0 = *(const bf16x8*)(bb + (size_t)(l15) * CC + k0);
            bf16x8 bv1 = *(const bf16x8*)(bb + (size_t)(16 + l15) * CC + k0);
            bf16x8 bv2 = *(const bf16x8*)(bb + (size_t)(32 + l15) * CC + k0);
            bf16x8 bv3 = *(const bf16x8*)(bb + (size_t)(48 + l15) * CC + k0);
            acc[0][0] = MFMA16(a0, bv0, acc[0][0], 0, 0, 0);
            acc[0][1] = MFMA16(a0, bv1, acc[0][1], 0, 0, 0);
            acc[0][2] = MFMA16(a0, bv2, acc[0][2], 0, 0, 0);
            acc[0][3] = MFMA16(a0, bv3, acc[0][3], 0, 0, 0);
            acc[1][0] = MFMA16(a1, bv0, acc[1][0], 0, 0, 0);
            acc[1][1] = MFMA16(a1, bv1, acc[1][1], 0, 0, 0);
            acc[1][2] = MFMA16(a1, bv2, acc[1][2], 0, 0, 0);
            acc[1][3] = MFMA16(a1, bv3, acc[1][3], 0, 0, 0);
        }
        // element: o = o0 + i*16 + lg*4 + r2 ; m = m0 + jj*16 + l15
        // voF idx = (((b*32 + m>>5)*16 + o>>4)*64 + ((m&31)>>3)*16 + (o&15))*8 + (m&7)
        u16* vbase = voF + (size_t)b * 32 * 16 * 512;
#pragma unroll
        for (int i = 0; i < 2; ++i)
#pragma unroll
            for (int jj = 0; jj < 4; ++jj)
#pragma unroll
                for (int r2 = 0; r2 < 4; ++r2) {
                    int mt32 = (m0 >> 5) + (jj >> 1);
                    int of   = (o0 >> 4) + i;
                    int mlg  = (jj & 1) * 2 + (l15 >> 3);
                    vbase[(((size_t)mt32 * 16 + of) * 64 + mlg * 16 + lg * 4 + r2) * 8 + (l15 & 7)]
                        = f2bf(acc[i][jj][r2]);
                }
    }
}

// ==== fused flash attention (MFMA) + epilogue ===============================
// 8 waves (512 thr), 64 q-rows; wave (wm,wo): m-half wm, o-slice wo*64,
// QK-tile wo of stream wm. All global reads are contiguous packed fragments.
__launch_bounds__(512, 4)
__global__ void attn_kernel(const u16* __restrict__ qF, const u16* __restrict__ kF,
                            const u16* __restrict__ voF, const float* __restrict__ x,
                            const float* __restrict__ gamma, float* __restrict__ out) {
    __shared__ __align__(16) u16   p_lds[2][2][64 * 40];  // [wm][buf][n][m] 20 KB
    __shared__ __align__(16) float rs_lds[2][64];

    const int t   = threadIdx.x;
    const int wv  = t >> 6, l = t & 63;
    const int wm  = wv >> 2, wo = wv & 3;
    const int l15 = l & 15, lg = l >> 4;
    const int b   = blockIdx.x & 7;              // batch -> XCD pin
    const int n0  = (blockIdx.x >> 3) << 6;      // 64-row tile

    // packed fragment bases (all wave-contiguous 1KB loads)
    bf16x8 qf = *(const bf16x8*)(qF + ((size_t)(b * 256 + (n0 >> 4) + wo) * 64 + l) * 8);
    const u16* kfp = kF  + ((size_t)(b * 64 + wm * 32) * 64 + l) * 8;
    const u16* vbl = voF + ((size_t)((b * 32 + wm * 16) * 16 + wo * 4) * 64 + l) * 8;

    u16*       pwp = &p_lds[wm][0][(wo * 16 + l15) * 40 + lg * 4];
    const u16* prp = &p_lds[wm][0][l15 * 40 + lg * 8];

    f32x4 acc[4][4];
    const f32x4 fz = {0.f, 0.f, 0.f, 0.f};
#pragma unroll
    for (int j = 0; j < 4; ++j)
#pragma unroll
        for (int of = 0; of < 4; ++of) acc[j][of] = fz;
    float rs = 0.f;

    bf16x8 kf0 = *(const bf16x8*)(kfp);
    bf16x8 kf1 = *(const bf16x8*)(kfp + 512);

#pragma unroll 2
    for (int i = 0; i < 16; ++i) {
        const int buf = i & 1;
        // ---- VO B-fragments: 4 contiguous 1KB wave-reads (4KB stream) -------
        bf16x8 vof[4];
#pragma unroll
        for (int of = 0; of < 4; ++of)
            vof[of] = *(const bf16x8*)(vbl + (size_t)i * 8192 + of * 512);
        // ---- S^T tile -------------------------------------------------------
        f32x4 c0 = MFMA16(kf0, qf, fz, 0, 0, 0);
        f32x4 c1 = MFMA16(kf1, qf, fz, 0, 0, 0);
        float e0 = __builtin_amdgcn_exp2f(c0[0]);
        float e1 = __builtin_amdgcn_exp2f(c0[1]);
        float e2 = __builtin_amdgcn_exp2f(c0[2]);
        float e3 = __builtin_amdgcn_exp2f(c0[3]);
        float e4 = __builtin_amdgcn_exp2f(c1[0]);
        float e5 = __builtin_amdgcn_exp2f(c1[1]);
        float e6 = __builtin_amdgcn_exp2f(c1[2]);
        float e7 = __builtin_amdgcn_exp2f(c1[3]);
        rs += (e0 + e1 + e2 + e3) + (e4 + e5 + e6 + e7);
        uint2 pw0, pw1;
        pw0.x = cvt_pk_bf16(e0, e1);
        pw0.y = cvt_pk_bf16(e2, e3);
        pw1.x = cvt_pk_bf16(e4, e5);
        pw1.y = cvt_pk_bf16(e6, e7);
        u16* pw = pwp + buf * 2560;
        *(uint2*)pw        = pw0;
        *(uint2*)(pw + 16) = pw1;
        // ---- barrier: drain LDS only; global loads stay outstanding ---------
        asm volatile("s_waitcnt lgkmcnt(0)" ::: "memory");
        __builtin_amdgcn_s_barrier();
        // ---- next-iter K prefetch -------------------------------------------
        bf16x8 kn0, kn1;
        if (i < 15) {
            kn0 = *(const bf16x8*)(kfp + (size_t)(i * 2 + 2) * 512);
            kn1 = *(const bf16x8*)(kfp + (size_t)(i * 2 + 3) * 512);
        }
        // ---- PV: 4 n-subtiles x 4 o-frags -----------------------------------
        const u16* pr = prp + buf * 2560;
#pragma unroll
        for (int j = 0; j < 4; ++j) {
            bf16x8 pa = *(const bf16x8*)(pr + j * 640);
#pragma unroll
            for (int of = 0; of < 4; ++of)
                acc[j][of] = MFMA16(pa, vof[of], acc[j][of], 0, 0, 0);
        }
        kf0 = kn0; kf1 = kn1;
    }

    // ---- row sums for this wave's 16 QK rows (half-m) -----------------------
    rs += __shfl_xor(rs, 16);
    rs += __shfl_xor(rs, 32);
    if (l < 16) rs_lds[wm][wo * 16 + l] = rs;

    // ---- combine m-half partials: wm=1 -> wm=0 via reused p_lds -------------
    __syncthreads();
    float* cbuf = (float*)p_lds;
#pragma unroll
    for (int r = 0; r < 4; ++r) {
        if (wm == 1) {
#pragma unroll
            for (int of = 0; of < 4; ++of)
                *(float4*)&cbuf[((wo * 64 + l) * 16) + of * 4] =
                    make_float4(acc[r][of][0], acc[r][of][1], acc[r][of][2], acc[r][of][3]);
        }
        __syncthreads();
        if (wm == 0) {
#pragma unroll
            for (int of = 0; of < 4; ++of) {
                float4 p = *(const float4*)&cbuf[((wo * 64 + l) * 16) + of * 4];
                acc[r][of][0] += p.x; acc[r][of][1] += p.y;
                acc[r][of][2] += p.z; acc[r][of][3] += p.w;
            }
        }
        __syncthreads();
    }

    // ---- epilogue (wm=0 waves): out[b][o][n] = x + g * O / rs ---------------
    if (wm == 0) {
        float g = gamma[0];
#pragma unroll
        for (int j = 0; j < 4; ++j) {
            float r0 = rs_lds[0][j * 16 + lg * 4 + 0] + rs_lds[1][j * 16 + lg * 4 + 0];
            float r1 = rs_lds[0][j * 16 + lg * 4 + 1] + rs_lds[1][j * 16 + lg * 4 + 1];
            float r2 = rs_lds[0][j * 16 + lg * 4 + 2] + rs_lds[1][j * 16 + lg * 4 + 2];
            float r3 = rs_lds[0][j * 16 + lg * 4 + 3] + rs_lds[1][j * 16 + lg * 4 + 3];
            float fa0 = g / r0, fa1 = g / r1, fa2 = g / r2, fa3 = g / r3;
#pragma unroll
            for (int of = 0; of < 4; ++of) {
                size_t base = ((size_t)(b * CC + wo * 64 + of * 16 + l15)) * NN
                            + n0 + j * 16 + lg * 4;
                float4 xv = *(const float4*)(x + base);
                float4 ov;
                ov.x = xv.x + acc[j][of][0] * fa0;
                ov.y = xv.y + acc[j][of][1] * fa1;
                ov.z = xv.z + acc[j][of][2] * fa2;
                ov.w = xv.w + acc[j][of][3] * fa3;
                *(float4*)(out + base) = ov;
            }
        }
    }
}

extern "C" void kernel_launch(void* const* d_in, const int* in_sizes, int n_in,
                              void* d_out, int out_size, void* d_ws, size_t ws_size,
                              hipStream_t stream) {
    const float* x     = (const float*)d_in[0];
    const float* wq    = (const float*)d_in[1];
    const float* wk    = (const float*)d_in[2];
    const float* wv    = (const float*)d_in[3];
    const float* wo    = (const float*)d_in[4];
    const float* gamma = (const float*)d_in[5];
    float* out = (float*)d_out;
    float* ws  = (float*)d_ws;

    u16* xkvT = (u16*)(ws + OFF_XKVT);
    u16* wvob = (u16*)(ws + OFF_WVO);
    u16* wqb  = (u16*)(ws + OFF_WQB);
    u16* wkb  = (u16*)(ws + OFF_WKB);
    u16* qF   = (u16*)(ws + OFF_QF);
    u16* kF   = (u16*)(ws + OFF_KF);
    u16* voF  = (u16*)(ws + OFF_VOF);
    u16* xT   = (u16*)d_out;     // 16 MB scratch in d_out; dead before attn writes

    prepw_kernel<<<dim3(1280), dim3(256), 0, stream>>>(x, wq, wk, wv, wo,
                                                       xT, xkvT, wqb, wkb, wvob);
    proj_kernel <<<dim3(576),  dim3(256), 0, stream>>>(xT, xkvT, wqb, wkb, wvob,
                                                       qF, kF, voF);
    attn_kernel <<<dim3(512),  dim3(512), 0, stream>>>(qF, kF, voF, x, gamma, out);
}

// Round 7
// 59.592 us; speedup vs baseline: 1.6000x; 1.1794x over previous
//
#include <hip/hip_runtime.h>

#define BB 8
#define CC 256
#define NN 4096
#define DD 32
#define NK 1024

typedef unsigned short u16;
typedef unsigned int   u32;
typedef __attribute__((ext_vector_type(8))) short bf16x8;
typedef __attribute__((ext_vector_type(4))) float f32x4;

#define MFMA16 __builtin_amdgcn_mfma_f32_16x16x32_bf16

// workspace offsets (in floats) — total 1,744,896 f = 7.0 MB
#define OFF_WVO  0u          // [CC][CC] bf16                 32,768 f
#define OFF_WQB  32768u      // [DD][CC] bf16                  4,096 f
#define OFF_WKB  36864u      // [DD][CC] bf16                  4,096 f
#define OFF_QF   40960u      // qF  [B][256 n16][64][8]      524,288 f
#define OFF_KF   565248u     // kF  [B][64 m16][64][8]       131,072 f
#define OFF_VOF  696320u     // voF [B][32 m32][16 o16][64][8] 1,048,576 f

__device__ __forceinline__ u16 f2bf(float f) {
    u32 u = __float_as_uint(f);
    u += 0x7FFFu + ((u >> 16) & 1u);      // RNE
    return (u16)(u >> 16);
}

__device__ __forceinline__ u32 cvt_pk_bf16(float lo, float hi) {
    u32 r;
    asm("v_cvt_pk_bf16_f32 %0, %1, %2" : "=v"(r) : "v"(lo), "v"(hi));
    return r;
}

// ==== weight prep: wvo = wo@wv (4-way split k + LDS reduce) + bf16 convs ====
__launch_bounds__(1024)
__global__ void wprep_kernel(const float* __restrict__ wq, const float* __restrict__ wk,
                             const float* __restrict__ wv, const float* __restrict__ wo,
                             u16* __restrict__ wqb, u16* __restrict__ wkb,
                             u16* __restrict__ wvob) {
    __shared__ float part[4][256];
    int o = blockIdx.x, t = threadIdx.x;
    int jq = t >> 8, c = t & 255;
    const float* wvp = wv + (size_t)(jq * 64) * CC + c;
    const float* wop = wo + o * CC + jq * 64;
    float acc = 0.f;
#pragma unroll 8
    for (int i = 0; i < 64; ++i)
        acc += wop[i] * wvp[(size_t)i * CC];
    part[jq][c] = acc;
    __syncthreads();
    if (t < 256)
        wvob[o * CC + t] = f2bf(part[0][t] + part[1][t] + part[2][t] + part[3][t]);
    if (o < 8) {
        const float QS = 0.17677669529663687f * 1.4426950408889634f; // 1/sqrt(32)*log2e
        int id = o * 1024 + t;                // 8192 = DD*CC
        wqb[id] = f2bf(wq[id] * QS);
    } else if (o < 16) {
        int id = (o - 8) * 1024 + t;
        wkb[id] = f2bf(wk[id]);
    }
}

// ==== projections directly from x (no intermediates) ========================
// blocks [0,256):  q-path.  b=blk&7, 128-n tile; LDS-staged transpose.
// blocks [256,512): k+vo.   b=blk2&7, pooled row hk (32 m); pool-on-the-fly.
__launch_bounds__(256)
__global__ void proj_kernel(const float* __restrict__ x,
                            const u16* __restrict__ wqb, const u16* __restrict__ wkb,
                            const u16* __restrict__ wvob,
                            u16* __restrict__ qF, u16* __restrict__ kF,
                            u16* __restrict__ voF) {
    int t = threadIdx.x, w = t >> 6, l = t & 63, l15 = l & 15, lg = l >> 4;
    const f32x4 fz = {0.f, 0.f, 0.f, 0.f};

    if (blockIdx.x < 256) {
        // ------------------- Q path -------------------
        __shared__ float xl[64 * 136];               // [c64][n128 pad136] 34.8 KB
        int b = blockIdx.x & 7, nb = blockIdx.x >> 3;
        int n0 = nb * 128;
        f32x4 acc[2][2];
        acc[0][0] = fz; acc[0][1] = fz; acc[1][0] = fz; acc[1][1] = fz;
        int cr = t >> 2, seg = (t & 3) * 32;
        for (int ch = 0; ch < 4; ++ch) {
            int c0 = ch * 64;
            const float* xs = x + ((size_t)(b * CC + c0 + cr)) * NN + n0 + seg;
#pragma unroll
            for (int p = 0; p < 8; ++p)
                *(float4*)&xl[cr * 136 + seg + p * 4] = *(const float4*)(xs + p * 4);
            __syncthreads();
#pragma unroll
            for (int ks = 0; ks < 2; ++ks) {
                int klo = ks * 32 + lg * 8;          // c-local base of this frag
                // A-frags: 2 n-tiles (rows w*32 + i*16 + l15)
#pragma unroll
                for (int i = 0; i < 2; ++i) {
                    int nl = w * 32 + i * 16 + l15;
                    float f0 = xl[(klo + 0) * 136 + nl];
                    float f1 = xl[(klo + 1) * 136 + nl];
                    float f2 = xl[(klo + 2) * 136 + nl];
                    float f3 = xl[(klo + 3) * 136 + nl];
                    float f4 = xl[(klo + 4) * 136 + nl];
                    float f5 = xl[(klo + 5) * 136 + nl];
                    float f6 = xl[(klo + 6) * 136 + nl];
                    float f7 = xl[(klo + 7) * 136 + nl];
                    union { u32 u[4]; bf16x8 v; } cv;
                    cv.u[0] = cvt_pk_bf16(f0, f1);
                    cv.u[1] = cvt_pk_bf16(f2, f3);
                    cv.u[2] = cvt_pk_bf16(f4, f5);
                    cv.u[3] = cvt_pk_bf16(f6, f7);
#pragma unroll
                    for (int dt = 0; dt < 2; ++dt) {
                        bf16x8 bq = *(const bf16x8*)(wqb + (size_t)(dt * 16 + l15) * CC + c0 + klo);
                        acc[i][dt] = MFMA16(cv.v, bq, acc[i][dt], 0, 0, 0);
                    }
                }
            }
            __syncthreads();
        }
        // scatter qF packed: tile = nb*8 + w*2 + i; element n-row lg*4+r2, d-col l15+16dt
        u16* outp = qF + (size_t)b * 256 * 512;
#pragma unroll
        for (int i = 0; i < 2; ++i)
#pragma unroll
            for (int dt = 0; dt < 2; ++dt)
#pragma unroll
                for (int r2 = 0; r2 < 4; ++r2) {
                    int tile = nb * 8 + w * 2 + i;
                    int dhi = dt * 2 + (l15 >> 3);
                    outp[((size_t)tile * 64 + dhi * 16 + lg * 4 + r2) * 8 + (l15 & 7)]
                        = f2bf(acc[i][dt][r2]);
                }
    } else {
        // ------------------- K + VO path -------------------
        __shared__ u16 pl[64 * 42];                  // pooled bf16 [c64][m32 pad42]
        int blk2 = blockIdx.x - 256;
        int b = blk2 & 7, hk = blk2 >> 3;            // pooled row hk, m0 = hk*32
        f32x4 acck = fz;
        f32x4 accv[2][4];
#pragma unroll
        for (int mt = 0; mt < 2; ++mt)
#pragma unroll
            for (int ot = 0; ot < 4; ++ot) accv[mt][ot] = fz;

        int cr = t >> 2, w8 = (t & 3) * 8;
        for (int ch = 0; ch < 4; ++ch) {
            int c0 = ch * 64;
            // pool 2x2: thread covers c = c0+cr, wk = w8..w8+7
            const float* xs = x + ((size_t)(b * CC + c0 + cr)) * NN + (2 * hk) * 64 + w8 * 2;
            float4 A0 = *(const float4*)(xs +  0), A1 = *(const float4*)(xs +  4);
            float4 A2 = *(const float4*)(xs +  8), A3 = *(const float4*)(xs + 12);
            float4 B0 = *(const float4*)(xs + 64), B1 = *(const float4*)(xs + 68);
            float4 B2 = *(const float4*)(xs + 72), B3 = *(const float4*)(xs + 76);
            float p0 = 0.25f * (A0.x + A0.y + B0.x + B0.y);
            float p1 = 0.25f * (A0.z + A0.w + B0.z + B0.w);
            float p2 = 0.25f * (A1.x + A1.y + B1.x + B1.y);
            float p3 = 0.25f * (A1.z + A1.w + B1.z + B1.w);
            float p4 = 0.25f * (A2.x + A2.y + B2.x + B2.y);
            float p5 = 0.25f * (A2.z + A2.w + B2.z + B2.w);
            float p6 = 0.25f * (A3.x + A3.y + B3.x + B3.y);
            float p7 = 0.25f * (A3.z + A3.w + B3.z + B3.w);
            u32* pw = (u32*)&pl[cr * 42 + w8];
            pw[0] = cvt_pk_bf16(p0, p1);
            pw[1] = cvt_pk_bf16(p2, p3);
            pw[2] = cvt_pk_bf16(p4, p5);
            pw[3] = cvt_pk_bf16(p6, p7);
            __syncthreads();
#pragma unroll
            for (int ks = 0; ks < 2; ++ks) {
                int klo = ks * 32 + lg * 8;
                // pooled fragments pm[mt]: element j = pooled[klo+j][mt*16+l15]
                bf16x8 pm[2];
#pragma unroll
                for (int mt = 0; mt < 2; ++mt) {
                    union { u16 s[8]; bf16x8 v; } cv;
#pragma unroll
                    for (int j = 0; j < 8; ++j)
                        cv.s[j] = pl[(klo + j) * 42 + mt * 16 + l15];
                    pm[mt] = cv.v;
                }
                // k projection: wave -> (m-tile w>>1, d-tile w&1)
                {
                    bf16x8 bk = *(const bf16x8*)(wkb + (size_t)((w & 1) * 16 + l15) * CC + c0 + klo);
                    acck = MFMA16(pm[w >> 1], bk, acck, 0, 0, 0);
                }
                // vo: wave o-slice w*64, 4 o-tiles x 2 m-tiles
#pragma unroll
                for (int ot = 0; ot < 4; ++ot) {
                    bf16x8 ao = *(const bf16x8*)(wvob + (size_t)(w * 64 + ot * 16 + l15) * CC + c0 + klo);
#pragma unroll
                    for (int mt = 0; mt < 2; ++mt)
                        accv[mt][ot] = MFMA16(ao, pm[mt], accv[mt][ot], 0, 0, 0);
                }
            }
            __syncthreads();
        }
        // scatter kF: element m = hk*32 + (w>>1)*16 + lg*4+r2, d = (w&1)*16 + l15
#pragma unroll
        for (int r2 = 0; r2 < 4; ++r2)
            kF[((size_t)(b * 64 + hk * 2 + (w >> 1)) * 64
                + ((w & 1) * 2 + (l15 >> 3)) * 16 + lg * 4 + r2) * 8 + (l15 & 7)]
                = f2bf(acck[r2]);
        // scatter voF: element o = w*64 + ot*16 + lg*4+r2, m = hk*32 + mt*16 + l15
#pragma unroll
        for (int mt = 0; mt < 2; ++mt)
#pragma unroll
            for (int ot = 0; ot < 4; ++ot)
#pragma unroll
                for (int r2 = 0; r2 < 4; ++r2)
                    voF[(((size_t)(b * 32 + hk) * 16 + w * 4 + ot) * 64
                         + (mt * 2 + (l15 >> 3)) * 16 + lg * 4 + r2) * 8 + (l15 & 7)]
                        = f2bf(accv[mt][ot][r2]);
    }
}

// ==== fused flash attention (MFMA) + epilogue ===============================
// 8 waves (512 thr), 64 q-rows; wave (wm,wo): m-half wm, o-slice wo*64,
// QK-tile wo of stream wm. All global reads are contiguous packed fragments.
__launch_bounds__(512, 4)
__global__ void attn_kernel(const u16* __restrict__ qF, const u16* __restrict__ kF,
                            const u16* __restrict__ voF, const float* __restrict__ x,
                            const float* __restrict__ gamma, float* __restrict__ out) {
    __shared__ __align__(16) u16   p_lds[2][2][64 * 40];  // [wm][buf][n][m] 20 KB
    __shared__ __align__(16) float rs_lds[2][64];

    const int t   = threadIdx.x;
    const int wv  = t >> 6, l = t & 63;
    const int wm  = wv >> 2, wo = wv & 3;
    const int l15 = l & 15, lg = l >> 4;
    const int b   = blockIdx.x & 7;              // batch -> XCD pin
    const int n0  = (blockIdx.x >> 3) << 6;      // 64-row tile

    // packed fragment bases (all wave-contiguous 1KB loads)
    bf16x8 qf = *(const bf16x8*)(qF + ((size_t)(b * 256 + (n0 >> 4) + wo) * 64 + l) * 8);
    const u16* kfp = kF  + ((size_t)(b * 64 + wm * 32) * 64 + l) * 8;
    const u16* vbl = voF + ((size_t)((b * 32 + wm * 16) * 16 + wo * 4) * 64 + l) * 8;

    u16*       pwp = &p_lds[wm][0][(wo * 16 + l15) * 40 + lg * 4];
    const u16* prp = &p_lds[wm][0][l15 * 40 + lg * 8];

    f32x4 acc[4][4];
    const f32x4 fz = {0.f, 0.f, 0.f, 0.f};
#pragma unroll
    for (int j = 0; j < 4; ++j)
#pragma unroll
        for (int of = 0; of < 4; ++of) acc[j][of] = fz;
    float rs = 0.f;

    bf16x8 kf0 = *(const bf16x8*)(kfp);
    bf16x8 kf1 = *(const bf16x8*)(kfp + 512);

#pragma unroll 2
    for (int i = 0; i < 16; ++i) {
        const int buf = i & 1;
        // ---- VO B-fragments: 4 contiguous 1KB wave-reads (4KB stream) -------
        bf16x8 vof[4];
#pragma unroll
        for (int of = 0; of < 4; ++of)
            vof[of] = *(const bf16x8*)(vbl + (size_t)i * 8192 + of * 512);
        // ---- S^T tile -------------------------------------------------------
        f32x4 c0 = MFMA16(kf0, qf, fz, 0, 0, 0);
        f32x4 c1 = MFMA16(kf1, qf, fz, 0, 0, 0);
        float e0 = __builtin_amdgcn_exp2f(c0[0]);
        float e1 = __builtin_amdgcn_exp2f(c0[1]);
        float e2 = __builtin_amdgcn_exp2f(c0[2]);
        float e3 = __builtin_amdgcn_exp2f(c0[3]);
        float e4 = __builtin_amdgcn_exp2f(c1[0]);
        float e5 = __builtin_amdgcn_exp2f(c1[1]);
        float e6 = __builtin_amdgcn_exp2f(c1[2]);
        float e7 = __builtin_amdgcn_exp2f(c1[3]);
        rs += (e0 + e1 + e2 + e3) + (e4 + e5 + e6 + e7);
        uint2 pw0, pw1;
        pw0.x = cvt_pk_bf16(e0, e1);
        pw0.y = cvt_pk_bf16(e2, e3);
        pw1.x = cvt_pk_bf16(e4, e5);
        pw1.y = cvt_pk_bf16(e6, e7);
        u16* pw = pwp + buf * 2560;
        *(uint2*)pw        = pw0;
        *(uint2*)(pw + 16) = pw1;
        // ---- barrier: drain LDS only; global loads stay outstanding ---------
        asm volatile("s_waitcnt lgkmcnt(0)" ::: "memory");
        __builtin_amdgcn_s_barrier();
        // ---- next-iter K prefetch -------------------------------------------
        bf16x8 kn0, kn1;
        if (i < 15) {
            kn0 = *(const bf16x8*)(kfp + (size_t)(i * 2 + 2) * 512);
            kn1 = *(const bf16x8*)(kfp + (size_t)(i * 2 + 3) * 512);
        }
        // ---- PV: 4 n-subtiles x 4 o-frags (setprio around MFMA cluster) -----
        const u16* pr = prp + buf * 2560;
        __builtin_amdgcn_s_setprio(1);
#pragma unroll
        for (int j = 0; j < 4; ++j) {
            bf16x8 pa = *(const bf16x8*)(pr + j * 640);
#pragma unroll
            for (int of = 0; of < 4; ++of)
                acc[j][of] = MFMA16(pa, vof[of], acc[j][of], 0, 0, 0);
        }
        __builtin_amdgcn_s_setprio(0);
        kf0 = kn0; kf1 = kn1;
    }

    // ---- row sums for this wave's 16 QK rows (half-m) -----------------------
    rs += __shfl_xor(rs, 16);
    rs += __shfl_xor(rs, 32);
    if (l < 16) rs_lds[wm][wo * 16 + l] = rs;

    // ---- combine m-half partials: wm=1 -> wm=0 via reused p_lds -------------
    __syncthreads();
    float* cbuf = (float*)p_lds;
#pragma unroll
    for (int r = 0; r < 4; ++r) {
        if (wm == 1) {
#pragma unroll
            for (int of = 0; of < 4; ++of)
                *(float4*)&cbuf[((wo * 64 + l) * 16) + of * 4] =
                    make_float4(acc[r][of][0], acc[r][of][1], acc[r][of][2], acc[r][of][3]);
        }
        __syncthreads();
        if (wm == 0) {
#pragma unroll
            for (int of = 0; of < 4; ++of) {
                float4 p = *(const float4*)&cbuf[((wo * 64 + l) * 16) + of * 4];
                acc[r][of][0] += p.x; acc[r][of][1] += p.y;
                acc[r][of][2] += p.z; acc[r][of][3] += p.w;
            }
        }
        __syncthreads();
    }

    // ---- epilogue (wm=0 waves): out[b][o][n] = x + g * O / rs ---------------
    if (wm == 0) {
        float g = gamma[0];
#pragma unroll
        for (int j = 0; j < 4; ++j) {
            float r0 = rs_lds[0][j * 16 + lg * 4 + 0] + rs_lds[1][j * 16 + lg * 4 + 0];
            float r1 = rs_lds[0][j * 16 + lg * 4 + 1] + rs_lds[1][j * 16 + lg * 4 + 1];
            float r2 = rs_lds[0][j * 16 + lg * 4 + 2] + rs_lds[1][j * 16 + lg * 4 + 2];
            float r3 = rs_lds[0][j * 16 + lg * 4 + 3] + rs_lds[1][j * 16 + lg * 4 + 3];
            float fa0 = g / r0, fa1 = g / r1, fa2 = g / r2, fa3 = g / r3;
#pragma unroll
            for (int of = 0; of < 4; ++of) {
                size_t base = ((size_t)(b * CC + wo * 64 + of * 16 + l15)) * NN
                            + n0 + j * 16 + lg * 4;
                float4 xv = *(const float4*)(x + base);
                float4 ov;
                ov.x = xv.x + acc[j][of][0] * fa0;
                ov.y = xv.y + acc[j][of][1] * fa1;
                ov.z = xv.z + acc[j][of][2] * fa2;
                ov.w = xv.w + acc[j][of][3] * fa3;
                *(float4*)(out + base) = ov;
            }
        }
    }
}

extern "C" void kernel_launch(void* const* d_in, const int* in_sizes, int n_in,
                              void* d_out, int out_size, void* d_ws, size_t ws_size,
                              hipStream_t stream) {
    const float* x     = (const float*)d_in[0];
    const float* wq    = (const float*)d_in[1];
    const float* wk    = (const float*)d_in[2];
    const float* wv    = (const float*)d_in[3];
    const float* wo    = (const float*)d_in[4];
    const float* gamma = (const float*)d_in[5];
    float* out = (float*)d_out;
    float* ws  = (float*)d_ws;

    u16* wvob = (u16*)(ws + OFF_WVO);
    u16* wqb  = (u16*)(ws + OFF_WQB);
    u16* wkb  = (u16*)(ws + OFF_WKB);
    u16* qF   = (u16*)(ws + OFF_QF);
    u16* kF   = (u16*)(ws + OFF_KF);
    u16* voF  = (u16*)(ws + OFF_VOF);

    wprep_kernel<<<dim3(256), dim3(1024), 0, stream>>>(wq, wk, wv, wo, wqb, wkb, wvob);
    proj_kernel <<<dim3(512), dim3(256),  0, stream>>>(x, wqb, wkb, wvob, qF, kF, voF);
    attn_kernel <<<dim3(512), dim3(512),  0, stream>>>(qF, kF, voF, x, gamma, out);
}